// Round 1
// baseline (472.702 us; speedup 1.0000x reference)
//
#include <hip/hip_runtime.h>

// ---------------------------------------------------------------------------
// GCN: 3-layer, N=50000 nodes, E=800000 edges, F_IN=128, H=128, C=64.
// Strategy:
//   deg/dinv + CSR(dst->src) built on device each launch (deterministic).
//   norm[e] = dinv[src]*dinv[dst]  =>  fold dinv into GEMM epilogue (rows of
//   h scaled by dinv) and aggregation epilogue.  Self-loop = + g[i].
//   layer: g = dinv .* (X @ W);  h = act(dinv[i]*(g[i] + sum_{j->i} g[j]) + b)
// ---------------------------------------------------------------------------

__global__ void count_k(const int* __restrict__ dst, int e, int* __restrict__ cnt) {
    int i = blockIdx.x * blockDim.x + threadIdx.x;
    if (i < e) atomicAdd(&cnt[dst[i]], 1);
}

// Single-block exclusive scan over cnt[n]; writes row_ptr, resets cnt to the
// running offset (reused as fill cursor), computes dinv = rsqrt(indeg+1).
__global__ __launch_bounds__(1024) void scan_k(int* __restrict__ cnt,
                                               int* __restrict__ row_ptr,
                                               float* __restrict__ dinv,
                                               int n, int e_total) {
    __shared__ int sums[1024];
    const int t = threadIdx.x;
    const int chunk = (n + 1023) >> 10;          // 49 for n=50000
    const int base = t * chunk;
    const int end = min(base + chunk, n);

    int s = 0;
    for (int j = base; j < end; ++j) s += cnt[j];
    sums[t] = s;
    __syncthreads();
    for (int off = 1; off < 1024; off <<= 1) {
        int v = (t >= off) ? sums[t - off] : 0;
        __syncthreads();
        sums[t] += v;
        __syncthreads();
    }
    int run = sums[t] - s;                        // exclusive prefix
    for (int j = base; j < end; ++j) {
        int c = cnt[j];
        row_ptr[j] = run;
        cnt[j] = run;                             // fill cursor
        dinv[j] = rsqrtf((float)(c + 1));         // +1 self-loop
        run += c;
    }
    if (t == 1023) row_ptr[n] = e_total;
}

__global__ void fill_k(const int* __restrict__ src, const int* __restrict__ dst,
                       int e, int* __restrict__ cursor, int* __restrict__ col) {
    int i = blockIdx.x * blockDim.x + threadIdx.x;
    if (i < e) {
        int p = atomicAdd(&cursor[dst[i]], 1);
        col[p] = src[i];
    }
}

// ---------------------------------------------------------------------------
// GEMM: G[r][c] = dinv[r] * sum_k X[r][k] * W[k][c];  K = 128 fixed.
// 128 rows/block, 256 threads as 16x16, each thread 8 rows x (OUT/16) cols.
// K staged through LDS in chunks of 32.
// ---------------------------------------------------------------------------
template <int OUT>
__global__ __launch_bounds__(256) void gemm_scale_k(const float* __restrict__ X,
                                                    const float* __restrict__ W,
                                                    const float* __restrict__ dinv,
                                                    float* __restrict__ G, int n) {
    constexpr int CPT = OUT / 16;                 // cols per thread: 8 or 4
    __shared__ float xs[128][33];                 // 32 k + 1 pad (stride 33)
    __shared__ float ws[32][OUT];

    const int tid = threadIdx.x;
    const int tx = tid & 15;
    const int ty = tid >> 4;
    const int row0 = blockIdx.x * 128;

    float acc[8][CPT];
#pragma unroll
    for (int i = 0; i < 8; ++i)
#pragma unroll
        for (int j = 0; j < CPT; ++j) acc[i][j] = 0.f;

    for (int kc = 0; kc < 4; ++kc) {
        __syncthreads();
        // stage X tile: 128 rows x 32 cols = 1024 float4
#pragma unroll
        for (int p = 0; p < 4; ++p) {
            int idx = p * 256 + tid;              // float4 index
            int r = idx >> 3;                     // 8 float4 per row
            int c4 = idx & 7;
            float4 v = make_float4(0.f, 0.f, 0.f, 0.f);
            if (row0 + r < n)
                v = *(const float4*)&X[(size_t)(row0 + r) * 128 + kc * 32 + c4 * 4];
            xs[r][c4 * 4 + 0] = v.x;
            xs[r][c4 * 4 + 1] = v.y;
            xs[r][c4 * 4 + 2] = v.z;
            xs[r][c4 * 4 + 3] = v.w;
        }
        // stage W tile: 32 rows x OUT cols
#pragma unroll
        for (int p = 0; p < (32 * OUT) / 1024; ++p) {
            int idx = p * 256 + tid;              // float4 index
            int r = idx / (OUT / 4);
            int c4 = idx % (OUT / 4);
            *(float4*)&ws[r][c4 * 4] =
                *(const float4*)&W[(size_t)(kc * 32 + r) * OUT + c4 * 4];
        }
        __syncthreads();
#pragma unroll 8
        for (int k = 0; k < 32; ++k) {
            float a[8], b[CPT];
#pragma unroll
            for (int i = 0; i < 8; ++i) a[i] = xs[ty * 8 + i][k];
#pragma unroll
            for (int j = 0; j < CPT; ++j) b[j] = ws[k][tx * CPT + j];
#pragma unroll
            for (int i = 0; i < 8; ++i)
#pragma unroll
                for (int j = 0; j < CPT; ++j) acc[i][j] += a[i] * b[j];
        }
    }

#pragma unroll
    for (int i = 0; i < 8; ++i) {
        int r = row0 + ty * 8 + i;
        if (r < n) {
            float d = dinv[r];
#pragma unroll
            for (int j4 = 0; j4 < CPT / 4; ++j4) {
                float4 o;
                o.x = d * acc[i][j4 * 4 + 0];
                o.y = d * acc[i][j4 * 4 + 1];
                o.z = d * acc[i][j4 * 4 + 2];
                o.w = d * acc[i][j4 * 4 + 3];
                *(float4*)&G[(size_t)r * OUT + tx * CPT + j4 * 4] = o;
            }
        }
    }
}

// ---------------------------------------------------------------------------
// Aggregation, hidden layers (OUT=128): one wave per node, lane = 2 columns.
// h[i] = swish(dinv[i]*(g[i] + sum_j g[j]) + b)
// ---------------------------------------------------------------------------
__global__ __launch_bounds__(256) void agg_swish_k(const float* __restrict__ G,
                                                   const int* __restrict__ rp,
                                                   const int* __restrict__ col,
                                                   const float* __restrict__ dinv,
                                                   const float* __restrict__ bias,
                                                   float* __restrict__ H, int n) {
    const int wave = (blockIdx.x * blockDim.x + threadIdx.x) >> 6;
    const int lane = threadIdx.x & 63;
    if (wave >= n) return;
    const int i = wave;
    const float2* g2 = (const float2*)G;          // row stride 64 float2

    float2 acc = g2[(size_t)i * 64 + lane];       // self-loop
    const int s = rp[i], e = rp[i + 1];
    int p = s;
    for (; p + 4 <= e; p += 4) {
        int j0 = col[p + 0], j1 = col[p + 1], j2 = col[p + 2], j3 = col[p + 3];
        float2 v0 = g2[(size_t)j0 * 64 + lane];
        float2 v1 = g2[(size_t)j1 * 64 + lane];
        float2 v2 = g2[(size_t)j2 * 64 + lane];
        float2 v3 = g2[(size_t)j3 * 64 + lane];
        acc.x += (v0.x + v1.x) + (v2.x + v3.x);
        acc.y += (v0.y + v1.y) + (v2.y + v3.y);
    }
    for (; p < e; ++p) {
        int j = col[p];
        float2 v = g2[(size_t)j * 64 + lane];
        acc.x += v.x;
        acc.y += v.y;
    }
    const float d = dinv[i];
    float rx = d * acc.x + bias[lane * 2 + 0];
    float ry = d * acc.y + bias[lane * 2 + 1];
    rx = rx / (1.f + expf(-rx));                  // swish
    ry = ry / (1.f + expf(-ry));
    float2 o;
    o.x = rx;
    o.y = ry;
    *(float2*)&H[(size_t)i * 128 + lane * 2] = o;
}

// ---------------------------------------------------------------------------
// Final aggregation (OUT=64) + log_softmax: one wave per node, lane = class.
// ---------------------------------------------------------------------------
__global__ __launch_bounds__(256) void agg_lsm_k(const float* __restrict__ G,
                                                 const int* __restrict__ rp,
                                                 const int* __restrict__ col,
                                                 const float* __restrict__ dinv,
                                                 const float* __restrict__ bias,
                                                 float* __restrict__ out, int n) {
    const int wave = (blockIdx.x * blockDim.x + threadIdx.x) >> 6;
    const int lane = threadIdx.x & 63;
    if (wave >= n) return;
    const int i = wave;

    float acc = G[(size_t)i * 64 + lane];         // self-loop
    const int s = rp[i], e = rp[i + 1];
    int p = s;
    for (; p + 4 <= e; p += 4) {
        int j0 = col[p + 0], j1 = col[p + 1], j2 = col[p + 2], j3 = col[p + 3];
        float v0 = G[(size_t)j0 * 64 + lane];
        float v1 = G[(size_t)j1 * 64 + lane];
        float v2 = G[(size_t)j2 * 64 + lane];
        float v3 = G[(size_t)j3 * 64 + lane];
        acc += (v0 + v1) + (v2 + v3);
    }
    for (; p < e; ++p) acc += G[(size_t)col[p] * 64 + lane];

    float logit = dinv[i] * acc + bias[lane];
    float m = logit;
#pragma unroll
    for (int off = 32; off > 0; off >>= 1) m = fmaxf(m, __shfl_xor(m, off));
    float ex = expf(logit - m);
    float ssum = ex;
#pragma unroll
    for (int off = 32; off > 0; off >>= 1) ssum += __shfl_xor(ssum, off);
    out[(size_t)i * 64 + lane] = logit - m - logf(ssum);
}

extern "C" void kernel_launch(void* const* d_in, const int* in_sizes, int n_in,
                              void* d_out, int out_size, void* d_ws, size_t ws_size,
                              hipStream_t stream) {
    const float* x = (const float*)d_in[0];
    const int* ei = (const int*)d_in[1];
    const float* W0 = (const float*)d_in[2];
    const float* b0 = (const float*)d_in[3];
    const float* W1 = (const float*)d_in[4];
    const float* b1 = (const float*)d_in[5];
    const float* W2 = (const float*)d_in[6];
    const float* b2 = (const float*)d_in[7];
    float* out = (float*)d_out;

    const int n = in_sizes[0] / 128;
    const int e = in_sizes[1] / 2;
    const int* src = ei;
    const int* dst = ei + e;

    char* ws = (char*)d_ws;
    size_t off = 0;
    auto alloc = [&](size_t bytes) -> void* {
        void* p = ws + off;
        off += (bytes + 255) & ~(size_t)255;
        return p;
    };
    int* cnt = (int*)alloc((size_t)n * 4);         // histogram -> fill cursor
    int* rp = (int*)alloc((size_t)(n + 1) * 4);    // CSR row_ptr
    float* dinv = (float*)alloc((size_t)n * 4);
    int* col = (int*)alloc((size_t)e * 4);         // CSR col (src per dst)
    float* g = (float*)alloc((size_t)n * 128 * 4); // pre-aggregation features
    float* h = (float*)alloc((size_t)n * 128 * 4); // post-activation features

    hipMemsetAsync(cnt, 0, (size_t)n * 4, stream);
    count_k<<<(e + 255) / 256, 256, 0, stream>>>(dst, e, cnt);
    scan_k<<<1, 1024, 0, stream>>>(cnt, rp, dinv, n, e);
    fill_k<<<(e + 255) / 256, 256, 0, stream>>>(src, dst, e, cnt, col);

    const int gb = (n + 127) / 128;
    const int ab = (n + 3) / 4;                    // 4 waves (nodes) per block

    gemm_scale_k<128><<<gb, 256, 0, stream>>>(x, W0, dinv, g, n);
    agg_swish_k<<<ab, 256, 0, stream>>>(g, rp, col, dinv, b0, h, n);
    gemm_scale_k<128><<<gb, 256, 0, stream>>>(h, W1, dinv, g, n);
    agg_swish_k<<<ab, 256, 0, stream>>>(g, rp, col, dinv, b1, h, n);
    gemm_scale_k<64><<<gb, 256, 0, stream>>>(h, W2, dinv, g, n);
    agg_lsm_k<<<ab, 256, 0, stream>>>(g, rp, col, dinv, b2, out, n);
}

// Round 2
// 350.148 us; speedup vs baseline: 1.3500x; 1.3500x over previous
//
#include <hip/hip_runtime.h>

// ---------------------------------------------------------------------------
// GCN: 3-layer, N=50000 nodes, E=800000 edges, F_IN=128, H=128, C=64.
//   deg/dinv + CSR(dst->src) built on device each launch (deterministic).
//   norm[e] = dinv[src]*dinv[dst]  =>  fold dinv into GEMM epilogue (rows of
//   h scaled by dinv) and aggregation epilogue.  Self-loop = + g[i].
//   layer: g = dinv .* (X @ W);  h = act(dinv[i]*(g[i] + sum_{j->i} g[j]) + b)
// R2: replaced 135us single-block scan with 3-kernel hierarchical scan.
// ---------------------------------------------------------------------------

__global__ void count_k(const int* __restrict__ dst, int e, int* __restrict__ cnt) {
    int i = blockIdx.x * blockDim.x + threadIdx.x;
    if (i < e) atomicAdd(&cnt[dst[i]], 1);
}

// K1: per-block (1024-element chunk) partial sums of cnt.
__global__ __launch_bounds__(256) void psum_k(const int* __restrict__ cnt, int n,
                                              int* __restrict__ bsum) {
    const int t = threadIdx.x;
    const int base = blockIdx.x * 1024 + t * 4;
    int s = 0;
    if (base + 3 < n) {
        int4 c = *(const int4*)&cnt[base];
        s = c.x + c.y + c.z + c.w;
    } else {
        for (int k = 0; k < 4; ++k)
            if (base + k < n) s += cnt[base + k];
    }
#pragma unroll
    for (int off = 32; off > 0; off >>= 1) s += __shfl_down(s, off);
    __shared__ int wsum[4];
    if ((t & 63) == 0) wsum[t >> 6] = s;
    __syncthreads();
    if (t == 0) bsum[blockIdx.x] = wsum[0] + wsum[1] + wsum[2] + wsum[3];
}

// K2: single-wave exclusive scan of the block sums (nb <= a few hundred).
__global__ __launch_bounds__(64) void bscan_k(int* __restrict__ bsum, int nb) {
    const int t = threadIdx.x;
    int carry = 0;
    for (int b = 0; b < nb; b += 64) {
        int i = b + t;
        int v = (i < nb) ? bsum[i] : 0;
        int x = v;
#pragma unroll
        for (int off = 1; off < 64; off <<= 1) {
            int y = __shfl_up(x, off);
            if (t >= off) x += y;
        }
        if (i < nb) bsum[i] = carry + x - v;     // exclusive + chunk carry
        carry += __shfl(x, 63);                  // total of this chunk
    }
}

// K3: per-block local exclusive scan + writeback: row_ptr, fill cursor
// (in-place over cnt), dinv = rsqrt(indeg+1).
__global__ __launch_bounds__(256) void scan2_k(int* __restrict__ cnt,
                                               const int* __restrict__ bsum,
                                               int* __restrict__ row_ptr,
                                               float* __restrict__ dinv,
                                               int n, int e_total) {
    __shared__ int tsum[256];
    const int t = threadIdx.x;
    const int base = blockIdx.x * 1024 + t * 4;
    int v[4] = {0, 0, 0, 0};
    if (base + 3 < n) {
        int4 c = *(const int4*)&cnt[base];
        v[0] = c.x; v[1] = c.y; v[2] = c.z; v[3] = c.w;
    } else {
        for (int k = 0; k < 4; ++k)
            if (base + k < n) v[k] = cnt[base + k];
    }
    int s = v[0] + v[1] + v[2] + v[3];
    tsum[t] = s;
    __syncthreads();
    for (int off = 1; off < 256; off <<= 1) {
        int x = (t >= off) ? tsum[t - off] : 0;
        __syncthreads();
        tsum[t] += x;
        __syncthreads();
    }
    int run = bsum[blockIdx.x] + tsum[t] - s;    // global exclusive prefix
#pragma unroll
    for (int k = 0; k < 4; ++k) {
        int idx = base + k;
        if (idx < n) {
            row_ptr[idx] = run;
            cnt[idx] = run;                      // fill cursor (in place)
            dinv[idx] = rsqrtf((float)(v[k] + 1));
            run += v[k];
        }
    }
    if (blockIdx.x == 0 && t == 0) row_ptr[n] = e_total;
}

__global__ void fill_k(const int* __restrict__ src, const int* __restrict__ dst,
                       int e, int* __restrict__ cursor, int* __restrict__ col) {
    int i = blockIdx.x * blockDim.x + threadIdx.x;
    if (i < e) {
        int p = atomicAdd(&cursor[dst[i]], 1);
        col[p] = src[i];
    }
}

// ---------------------------------------------------------------------------
// GEMM: G[r][c] = dinv[r] * sum_k X[r][k] * W[k][c];  K = 128 fixed.
// 128 rows/block, 256 threads as 16x16, each thread 8 rows x (OUT/16) cols.
// ---------------------------------------------------------------------------
template <int OUT>
__global__ __launch_bounds__(256) void gemm_scale_k(const float* __restrict__ X,
                                                    const float* __restrict__ W,
                                                    const float* __restrict__ dinv,
                                                    float* __restrict__ G, int n) {
    constexpr int CPT = OUT / 16;                 // cols per thread: 8 or 4
    __shared__ float xs[128][33];                 // 32 k + 1 pad (stride 33)
    __shared__ float ws[32][OUT];

    const int tid = threadIdx.x;
    const int tx = tid & 15;
    const int ty = tid >> 4;
    const int row0 = blockIdx.x * 128;

    float acc[8][CPT];
#pragma unroll
    for (int i = 0; i < 8; ++i)
#pragma unroll
        for (int j = 0; j < CPT; ++j) acc[i][j] = 0.f;

    for (int kc = 0; kc < 4; ++kc) {
        __syncthreads();
#pragma unroll
        for (int p = 0; p < 4; ++p) {
            int idx = p * 256 + tid;              // float4 index
            int r = idx >> 3;                     // 8 float4 per row
            int c4 = idx & 7;
            float4 v = make_float4(0.f, 0.f, 0.f, 0.f);
            if (row0 + r < n)
                v = *(const float4*)&X[(size_t)(row0 + r) * 128 + kc * 32 + c4 * 4];
            xs[r][c4 * 4 + 0] = v.x;
            xs[r][c4 * 4 + 1] = v.y;
            xs[r][c4 * 4 + 2] = v.z;
            xs[r][c4 * 4 + 3] = v.w;
        }
#pragma unroll
        for (int p = 0; p < (32 * OUT) / 1024; ++p) {
            int idx = p * 256 + tid;              // float4 index
            int r = idx / (OUT / 4);
            int c4 = idx % (OUT / 4);
            *(float4*)&ws[r][c4 * 4] =
                *(const float4*)&W[(size_t)(kc * 32 + r) * OUT + c4 * 4];
        }
        __syncthreads();
#pragma unroll 8
        for (int k = 0; k < 32; ++k) {
            float a[8], b[CPT];
#pragma unroll
            for (int i = 0; i < 8; ++i) a[i] = xs[ty * 8 + i][k];
#pragma unroll
            for (int j = 0; j < CPT; ++j) b[j] = ws[k][tx * CPT + j];
#pragma unroll
            for (int i = 0; i < 8; ++i)
#pragma unroll
                for (int j = 0; j < CPT; ++j) acc[i][j] += a[i] * b[j];
        }
    }

#pragma unroll
    for (int i = 0; i < 8; ++i) {
        int r = row0 + ty * 8 + i;
        if (r < n) {
            float d = dinv[r];
#pragma unroll
            for (int j4 = 0; j4 < CPT / 4; ++j4) {
                float4 o;
                o.x = d * acc[i][j4 * 4 + 0];
                o.y = d * acc[i][j4 * 4 + 1];
                o.z = d * acc[i][j4 * 4 + 2];
                o.w = d * acc[i][j4 * 4 + 3];
                *(float4*)&G[(size_t)r * OUT + tx * CPT + j4 * 4] = o;
            }
        }
    }
}

// ---------------------------------------------------------------------------
// Aggregation, hidden layers (OUT=128): one wave per node, lane = 2 columns.
// ---------------------------------------------------------------------------
__global__ __launch_bounds__(256) void agg_swish_k(const float* __restrict__ G,
                                                   const int* __restrict__ rp,
                                                   const int* __restrict__ col,
                                                   const float* __restrict__ dinv,
                                                   const float* __restrict__ bias,
                                                   float* __restrict__ H, int n) {
    const int wave = (blockIdx.x * blockDim.x + threadIdx.x) >> 6;
    const int lane = threadIdx.x & 63;
    if (wave >= n) return;
    const int i = wave;
    const float2* g2 = (const float2*)G;          // row stride 64 float2

    float2 acc = g2[(size_t)i * 64 + lane];       // self-loop
    const int s = rp[i], e = rp[i + 1];
    int p = s;
    for (; p + 4 <= e; p += 4) {
        int j0 = col[p + 0], j1 = col[p + 1], j2 = col[p + 2], j3 = col[p + 3];
        float2 v0 = g2[(size_t)j0 * 64 + lane];
        float2 v1 = g2[(size_t)j1 * 64 + lane];
        float2 v2 = g2[(size_t)j2 * 64 + lane];
        float2 v3 = g2[(size_t)j3 * 64 + lane];
        acc.x += (v0.x + v1.x) + (v2.x + v3.x);
        acc.y += (v0.y + v1.y) + (v2.y + v3.y);
    }
    for (; p < e; ++p) {
        int j = col[p];
        float2 v = g2[(size_t)j * 64 + lane];
        acc.x += v.x;
        acc.y += v.y;
    }
    const float d = dinv[i];
    float rx = d * acc.x + bias[lane * 2 + 0];
    float ry = d * acc.y + bias[lane * 2 + 1];
    rx = rx / (1.f + expf(-rx));                  // swish
    ry = ry / (1.f + expf(-ry));
    float2 o;
    o.x = rx;
    o.y = ry;
    *(float2*)&H[(size_t)i * 128 + lane * 2] = o;
}

// ---------------------------------------------------------------------------
// Final aggregation (OUT=64) + log_softmax: one wave per node, lane = class.
// ---------------------------------------------------------------------------
__global__ __launch_bounds__(256) void agg_lsm_k(const float* __restrict__ G,
                                                 const int* __restrict__ rp,
                                                 const int* __restrict__ col,
                                                 const float* __restrict__ dinv,
                                                 const float* __restrict__ bias,
                                                 float* __restrict__ out, int n) {
    const int wave = (blockIdx.x * blockDim.x + threadIdx.x) >> 6;
    const int lane = threadIdx.x & 63;
    if (wave >= n) return;
    const int i = wave;

    float acc = G[(size_t)i * 64 + lane];         // self-loop
    const int s = rp[i], e = rp[i + 1];
    int p = s;
    for (; p + 4 <= e; p += 4) {
        int j0 = col[p + 0], j1 = col[p + 1], j2 = col[p + 2], j3 = col[p + 3];
        float v0 = G[(size_t)j0 * 64 + lane];
        float v1 = G[(size_t)j1 * 64 + lane];
        float v2 = G[(size_t)j2 * 64 + lane];
        float v3 = G[(size_t)j3 * 64 + lane];
        acc += (v0 + v1) + (v2 + v3);
    }
    for (; p < e; ++p) acc += G[(size_t)col[p] * 64 + lane];

    float logit = dinv[i] * acc + bias[lane];
    float m = logit;
#pragma unroll
    for (int off = 32; off > 0; off >>= 1) m = fmaxf(m, __shfl_xor(m, off));
    float ex = expf(logit - m);
    float ssum = ex;
#pragma unroll
    for (int off = 32; off > 0; off >>= 1) ssum += __shfl_xor(ssum, off);
    out[(size_t)i * 64 + lane] = logit - m - logf(ssum);
}

extern "C" void kernel_launch(void* const* d_in, const int* in_sizes, int n_in,
                              void* d_out, int out_size, void* d_ws, size_t ws_size,
                              hipStream_t stream) {
    const float* x = (const float*)d_in[0];
    const int* ei = (const int*)d_in[1];
    const float* W0 = (const float*)d_in[2];
    const float* b0 = (const float*)d_in[3];
    const float* W1 = (const float*)d_in[4];
    const float* b1 = (const float*)d_in[5];
    const float* W2 = (const float*)d_in[6];
    const float* b2 = (const float*)d_in[7];
    float* out = (float*)d_out;

    const int n = in_sizes[0] / 128;
    const int e = in_sizes[1] / 2;
    const int* src = ei;
    const int* dst = ei + e;

    char* ws = (char*)d_ws;
    size_t off = 0;
    auto alloc = [&](size_t bytes) -> void* {
        void* p = ws + off;
        off += (bytes + 255) & ~(size_t)255;
        return p;
    };
    int* cnt = (int*)alloc((size_t)n * 4);         // histogram -> fill cursor
    int* rp = (int*)alloc((size_t)(n + 1) * 4);    // CSR row_ptr
    float* dinv = (float*)alloc((size_t)n * 4);
    int* col = (int*)alloc((size_t)e * 4);         // CSR col (src per dst)
    int* bsum = (int*)alloc(4096);                 // block partial sums
    float* g = (float*)alloc((size_t)n * 128 * 4); // pre-aggregation features
    float* h = (float*)alloc((size_t)n * 128 * 4); // post-activation features

    const int nb = (n + 1023) / 1024;              // scan blocks (49)

    hipMemsetAsync(cnt, 0, (size_t)n * 4, stream);
    count_k<<<(e + 255) / 256, 256, 0, stream>>>(dst, e, cnt);
    psum_k<<<nb, 256, 0, stream>>>(cnt, n, bsum);
    bscan_k<<<1, 64, 0, stream>>>(bsum, nb);
    scan2_k<<<nb, 256, 0, stream>>>(cnt, bsum, rp, dinv, n, e);
    fill_k<<<(e + 255) / 256, 256, 0, stream>>>(src, dst, e, cnt, col);

    const int gb = (n + 127) / 128;
    const int ab = (n + 3) / 4;                    // 4 waves (nodes) per block

    gemm_scale_k<128><<<gb, 256, 0, stream>>>(x, W0, dinv, g, n);
    agg_swish_k<<<ab, 256, 0, stream>>>(g, rp, col, dinv, b0, h, n);
    gemm_scale_k<128><<<gb, 256, 0, stream>>>(h, W1, dinv, g, n);
    agg_swish_k<<<ab, 256, 0, stream>>>(g, rp, col, dinv, b1, h, n);
    gemm_scale_k<64><<<gb, 256, 0, stream>>>(h, W2, dinv, g, n);
    agg_lsm_k<<<ab, 256, 0, stream>>>(g, rp, col, dinv, b2, out, n);
}

// Round 3
// 310.303 us; speedup vs baseline: 1.5234x; 1.1284x over previous
//
#include <hip/hip_runtime.h>

// ---------------------------------------------------------------------------
// GCN: 3-layer, N=50000 nodes, E=800000 edges, F_IN=128, H=128, C=64.
//   deg/dinv + CSR(dst->src) built on device each launch (deterministic).
//   norm[e] = dinv[src]*dinv[dst]  =>  fold dinv into GEMM epilogue (rows of
//   h scaled by dinv) and aggregation epilogue.  Self-loop = + g[i].
//   layer: g = dinv .* (X @ W);  h = act(dinv[i]*(g[i] + sum_{j->i} g[j]) + b)
// R2: hierarchical scan (135us -> ~5us).
// R3: G stored bf16 (packed in GEMM epilogue) -> gather traffic halved;
//     f32 accumulation in agg kernels. H stays f32 (GEMM input).
// ---------------------------------------------------------------------------

__device__ inline unsigned bf16_rn(float x) {          // rne, no NaN expected
    unsigned u = __float_as_uint(x);
    return (u + 0x7fffu + ((u >> 16) & 1u)) >> 16;
}
__device__ inline float bf_lo(unsigned u) { return __uint_as_float(u << 16); }
__device__ inline float bf_hi(unsigned u) { return __uint_as_float(u & 0xffff0000u); }

__global__ void count_k(const int* __restrict__ dst, int e, int* __restrict__ cnt) {
    int i = blockIdx.x * blockDim.x + threadIdx.x;
    if (i < e) atomicAdd(&cnt[dst[i]], 1);
}

// K1: per-block (1024-element chunk) partial sums of cnt.
__global__ __launch_bounds__(256) void psum_k(const int* __restrict__ cnt, int n,
                                              int* __restrict__ bsum) {
    const int t = threadIdx.x;
    const int base = blockIdx.x * 1024 + t * 4;
    int s = 0;
    if (base + 3 < n) {
        int4 c = *(const int4*)&cnt[base];
        s = c.x + c.y + c.z + c.w;
    } else {
        for (int k = 0; k < 4; ++k)
            if (base + k < n) s += cnt[base + k];
    }
#pragma unroll
    for (int off = 32; off > 0; off >>= 1) s += __shfl_down(s, off);
    __shared__ int wsum[4];
    if ((t & 63) == 0) wsum[t >> 6] = s;
    __syncthreads();
    if (t == 0) bsum[blockIdx.x] = wsum[0] + wsum[1] + wsum[2] + wsum[3];
}

// K2: single-wave exclusive scan of the block sums.
__global__ __launch_bounds__(64) void bscan_k(int* __restrict__ bsum, int nb) {
    const int t = threadIdx.x;
    int carry = 0;
    for (int b = 0; b < nb; b += 64) {
        int i = b + t;
        int v = (i < nb) ? bsum[i] : 0;
        int x = v;
#pragma unroll
        for (int off = 1; off < 64; off <<= 1) {
            int y = __shfl_up(x, off);
            if (t >= off) x += y;
        }
        if (i < nb) bsum[i] = carry + x - v;     // exclusive + chunk carry
        carry += __shfl(x, 63);                  // total of this chunk
    }
}

// K3: per-block local exclusive scan + writeback: row_ptr, fill cursor
// (in-place over cnt), dinv = rsqrt(indeg+1).
__global__ __launch_bounds__(256) void scan2_k(int* __restrict__ cnt,
                                               const int* __restrict__ bsum,
                                               int* __restrict__ row_ptr,
                                               float* __restrict__ dinv,
                                               int n, int e_total) {
    __shared__ int tsum[256];
    const int t = threadIdx.x;
    const int base = blockIdx.x * 1024 + t * 4;
    int v[4] = {0, 0, 0, 0};
    if (base + 3 < n) {
        int4 c = *(const int4*)&cnt[base];
        v[0] = c.x; v[1] = c.y; v[2] = c.z; v[3] = c.w;
    } else {
        for (int k = 0; k < 4; ++k)
            if (base + k < n) v[k] = cnt[base + k];
    }
    int s = v[0] + v[1] + v[2] + v[3];
    tsum[t] = s;
    __syncthreads();
    for (int off = 1; off < 256; off <<= 1) {
        int x = (t >= off) ? tsum[t - off] : 0;
        __syncthreads();
        tsum[t] += x;
        __syncthreads();
    }
    int run = bsum[blockIdx.x] + tsum[t] - s;    // global exclusive prefix
#pragma unroll
    for (int k = 0; k < 4; ++k) {
        int idx = base + k;
        if (idx < n) {
            row_ptr[idx] = run;
            cnt[idx] = run;                      // fill cursor (in place)
            dinv[idx] = rsqrtf((float)(v[k] + 1));
            run += v[k];
        }
    }
    if (blockIdx.x == 0 && t == 0) row_ptr[n] = e_total;
}

__global__ void fill_k(const int* __restrict__ src, const int* __restrict__ dst,
                       int e, int* __restrict__ cursor, int* __restrict__ col) {
    int i = blockIdx.x * blockDim.x + threadIdx.x;
    if (i < e) {
        int p = atomicAdd(&cursor[dst[i]], 1);
        col[p] = src[i];
    }
}

// ---------------------------------------------------------------------------
// GEMM: G[r][c] = dinv[r] * sum_k X[r][k] * W[k][c];  K = 128 fixed.
// 128 rows/block, 256 threads as 16x16, each thread 8 rows x (OUT/16) cols.
// Output stored as packed bf16 (2 cols per uint).
// ---------------------------------------------------------------------------
template <int OUT>
__global__ __launch_bounds__(256) void gemm_scale_k(const float* __restrict__ X,
                                                    const float* __restrict__ W,
                                                    const float* __restrict__ dinv,
                                                    unsigned* __restrict__ Gb, int n) {
    constexpr int CPT = OUT / 16;                 // cols per thread: 8 or 4
    __shared__ float xs[128][33];                 // 32 k + 1 pad (stride 33)
    __shared__ float ws[32][OUT];

    const int tid = threadIdx.x;
    const int tx = tid & 15;
    const int ty = tid >> 4;
    const int row0 = blockIdx.x * 128;

    float acc[8][CPT];
#pragma unroll
    for (int i = 0; i < 8; ++i)
#pragma unroll
        for (int j = 0; j < CPT; ++j) acc[i][j] = 0.f;

    for (int kc = 0; kc < 4; ++kc) {
        __syncthreads();
#pragma unroll
        for (int p = 0; p < 4; ++p) {
            int idx = p * 256 + tid;              // float4 index
            int r = idx >> 3;                     // 8 float4 per row
            int c4 = idx & 7;
            float4 v = make_float4(0.f, 0.f, 0.f, 0.f);
            if (row0 + r < n)
                v = *(const float4*)&X[(size_t)(row0 + r) * 128 + kc * 32 + c4 * 4];
            xs[r][c4 * 4 + 0] = v.x;
            xs[r][c4 * 4 + 1] = v.y;
            xs[r][c4 * 4 + 2] = v.z;
            xs[r][c4 * 4 + 3] = v.w;
        }
#pragma unroll
        for (int p = 0; p < (32 * OUT) / 1024; ++p) {
            int idx = p * 256 + tid;              // float4 index
            int r = idx / (OUT / 4);
            int c4 = idx % (OUT / 4);
            *(float4*)&ws[r][c4 * 4] =
                *(const float4*)&W[(size_t)(kc * 32 + r) * OUT + c4 * 4];
        }
        __syncthreads();
#pragma unroll 8
        for (int k = 0; k < 32; ++k) {
            float a[8], b[CPT];
#pragma unroll
            for (int i = 0; i < 8; ++i) a[i] = xs[ty * 8 + i][k];
#pragma unroll
            for (int j = 0; j < CPT; ++j) b[j] = ws[k][tx * CPT + j];
#pragma unroll
            for (int i = 0; i < 8; ++i)
#pragma unroll
                for (int j = 0; j < CPT; ++j) acc[i][j] += a[i] * b[j];
        }
    }

    // epilogue: scale by dinv[r], pack to bf16 (2 cols / uint)
#pragma unroll
    for (int i = 0; i < 8; ++i) {
        int r = row0 + ty * 8 + i;
        if (r < n) {
            float d = dinv[r];
            unsigned pk[CPT / 2];
#pragma unroll
            for (int j = 0; j < CPT / 2; ++j)
                pk[j] = bf16_rn(d * acc[i][j * 2]) |
                        (bf16_rn(d * acc[i][j * 2 + 1]) << 16);
            unsigned* rowp = &Gb[(size_t)r * (OUT / 2) + tx * (CPT / 2)];
            if (CPT == 8) *(uint4*)rowp = make_uint4(pk[0], pk[1], pk[2], pk[3]);
            else          *(uint2*)rowp = make_uint2(pk[0], pk[1]);
        }
    }
}

// ---------------------------------------------------------------------------
// Aggregation, hidden layers (OUT=128): one wave per node, lane = 2 columns
// (one packed-bf16 uint per lane).  f32 accumulate, swish, f32 H out.
// ---------------------------------------------------------------------------
__global__ __launch_bounds__(256) void agg_swish_k(const unsigned* __restrict__ G,
                                                   const int* __restrict__ rp,
                                                   const int* __restrict__ col,
                                                   const float* __restrict__ dinv,
                                                   const float* __restrict__ bias,
                                                   float* __restrict__ H, int n) {
    const int wave = (blockIdx.x * blockDim.x + threadIdx.x) >> 6;
    const int lane = threadIdx.x & 63;
    if (wave >= n) return;
    const int i = wave;

    unsigned u = G[(size_t)i * 64 + lane];        // self-loop (row = 64 uints)
    float ax = bf_lo(u), ay = bf_hi(u);
    const int s = rp[i], e = rp[i + 1];
    int p = s;
    for (; p + 4 <= e; p += 4) {
        int j0 = col[p + 0], j1 = col[p + 1], j2 = col[p + 2], j3 = col[p + 3];
        unsigned u0 = G[(size_t)j0 * 64 + lane];
        unsigned u1 = G[(size_t)j1 * 64 + lane];
        unsigned u2 = G[(size_t)j2 * 64 + lane];
        unsigned u3 = G[(size_t)j3 * 64 + lane];
        ax += (bf_lo(u0) + bf_lo(u1)) + (bf_lo(u2) + bf_lo(u3));
        ay += (bf_hi(u0) + bf_hi(u1)) + (bf_hi(u2) + bf_hi(u3));
    }
    for (; p < e; ++p) {
        unsigned v = G[(size_t)col[p] * 64 + lane];
        ax += bf_lo(v);
        ay += bf_hi(v);
    }
    const float d = dinv[i];
    float rx = d * ax + bias[lane * 2 + 0];
    float ry = d * ay + bias[lane * 2 + 1];
    rx = rx / (1.f + expf(-rx));                  // swish
    ry = ry / (1.f + expf(-ry));
    float2 o;
    o.x = rx;
    o.y = ry;
    *(float2*)&H[(size_t)i * 128 + lane * 2] = o;
}

// ---------------------------------------------------------------------------
// Final aggregation (OUT=64, bf16 rows of 128B) + log_softmax.
// One wave per node, lane = class (ushort load per edge).
// ---------------------------------------------------------------------------
__global__ __launch_bounds__(256) void agg_lsm_k(const unsigned short* __restrict__ G,
                                                 const int* __restrict__ rp,
                                                 const int* __restrict__ col,
                                                 const float* __restrict__ dinv,
                                                 const float* __restrict__ bias,
                                                 float* __restrict__ out, int n) {
    const int wave = (blockIdx.x * blockDim.x + threadIdx.x) >> 6;
    const int lane = threadIdx.x & 63;
    if (wave >= n) return;
    const int i = wave;

    float acc = __uint_as_float((unsigned)G[(size_t)i * 64 + lane] << 16);
    const int s = rp[i], e = rp[i + 1];
    int p = s;
    for (; p + 4 <= e; p += 4) {
        int j0 = col[p + 0], j1 = col[p + 1], j2 = col[p + 2], j3 = col[p + 3];
        float v0 = __uint_as_float((unsigned)G[(size_t)j0 * 64 + lane] << 16);
        float v1 = __uint_as_float((unsigned)G[(size_t)j1 * 64 + lane] << 16);
        float v2 = __uint_as_float((unsigned)G[(size_t)j2 * 64 + lane] << 16);
        float v3 = __uint_as_float((unsigned)G[(size_t)j3 * 64 + lane] << 16);
        acc += (v0 + v1) + (v2 + v3);
    }
    for (; p < e; ++p)
        acc += __uint_as_float((unsigned)G[(size_t)col[p] * 64 + lane] << 16);

    float logit = dinv[i] * acc + bias[lane];
    float m = logit;
#pragma unroll
    for (int off = 32; off > 0; off >>= 1) m = fmaxf(m, __shfl_xor(m, off));
    float ex = expf(logit - m);
    float ssum = ex;
#pragma unroll
    for (int off = 32; off > 0; off >>= 1) ssum += __shfl_xor(ssum, off);
    out[(size_t)i * 64 + lane] = logit - m - logf(ssum);
}

extern "C" void kernel_launch(void* const* d_in, const int* in_sizes, int n_in,
                              void* d_out, int out_size, void* d_ws, size_t ws_size,
                              hipStream_t stream) {
    const float* x = (const float*)d_in[0];
    const int* ei = (const int*)d_in[1];
    const float* W0 = (const float*)d_in[2];
    const float* b0 = (const float*)d_in[3];
    const float* W1 = (const float*)d_in[4];
    const float* b1 = (const float*)d_in[5];
    const float* W2 = (const float*)d_in[6];
    const float* b2 = (const float*)d_in[7];
    float* out = (float*)d_out;

    const int n = in_sizes[0] / 128;
    const int e = in_sizes[1] / 2;
    const int* src = ei;
    const int* dst = ei + e;

    char* ws = (char*)d_ws;
    size_t off = 0;
    auto alloc = [&](size_t bytes) -> void* {
        void* p = ws + off;
        off += (bytes + 255) & ~(size_t)255;
        return p;
    };
    int* cnt = (int*)alloc((size_t)n * 4);         // histogram -> fill cursor
    int* rp = (int*)alloc((size_t)(n + 1) * 4);    // CSR row_ptr
    float* dinv = (float*)alloc((size_t)n * 4);
    int* col = (int*)alloc((size_t)e * 4);         // CSR col (src per dst)
    int* bsum = (int*)alloc(4096);                 // block partial sums
    unsigned* g = (unsigned*)alloc((size_t)n * 64 * 4); // bf16 pre-agg features
    float* h = (float*)alloc((size_t)n * 128 * 4); // post-activation features

    const int nb = (n + 1023) / 1024;              // scan blocks (49)

    hipMemsetAsync(cnt, 0, (size_t)n * 4, stream);
    count_k<<<(e + 255) / 256, 256, 0, stream>>>(dst, e, cnt);
    psum_k<<<nb, 256, 0, stream>>>(cnt, n, bsum);
    bscan_k<<<1, 64, 0, stream>>>(bsum, nb);
    scan2_k<<<nb, 256, 0, stream>>>(cnt, bsum, rp, dinv, n, e);
    fill_k<<<(e + 255) / 256, 256, 0, stream>>>(src, dst, e, cnt, col);

    const int gb = (n + 127) / 128;
    const int ab = (n + 3) / 4;                    // 4 waves (nodes) per block

    gemm_scale_k<128><<<gb, 256, 0, stream>>>(x, W0, dinv, g, n);
    agg_swish_k<<<ab, 256, 0, stream>>>(g, rp, col, dinv, b0, h, n);
    gemm_scale_k<128><<<gb, 256, 0, stream>>>(h, W1, dinv, g, n);
    agg_swish_k<<<ab, 256, 0, stream>>>(g, rp, col, dinv, b1, h, n);
    gemm_scale_k<64><<<gb, 256, 0, stream>>>(h, W2, dinv, g, n);
    agg_lsm_k<<<ab, 256, 0, stream>>>((const unsigned short*)g, rp, col, dinv, b2, out, n);
}

// Round 4
// 261.286 us; speedup vs baseline: 1.8091x; 1.1876x over previous
//
#include <hip/hip_runtime.h>

// ---------------------------------------------------------------------------
// GCN: 3-layer, N=50000 nodes, E=800000 edges, F_IN=128, H=128, C=64.
//   norm[e] = dinv[src]*dinv[dst]  =>  fold dinv into GEMM epilogue (rows of
//   h scaled by dinv) and aggregation epilogue.  Self-loop = + g[i].
//   layer: g = dinv .* (X @ W);  h = act(dinv[i]*(g[i] + sum_{j->i} g[j]) + b)
// R2: hierarchical scan. R3: G stored bf16 -> gather traffic halved.
// R4: graph build rewritten as bucketed counting sort. Old fill_k did 800K
//     random 4B writes -> 52MB partial-line writeback at ~1TB/s (53us).
//     Now: bucket histogram -> block-chunked pair scatter (single-writer
//     chunks) -> per-bucket CSR build (each workgroup owns its 65KB col
//     segment; scattered writes stay in one XCD's L2, full-line writeback).
// ---------------------------------------------------------------------------

#define NODES_PER_BUCKET 1024      // bucket = dst >> 10
#define MAX_BUCKETS 64             // n <= 64K nodes (50000 -> 49 buckets)

__device__ inline unsigned bf16_rn(float x) {          // rne, no NaN expected
    unsigned u = __float_as_uint(x);
    return (u + 0x7fffu + ((u >> 16) & 1u)) >> 16;
}
__device__ inline float bf_lo(unsigned u) { return __uint_as_float(u << 16); }
__device__ inline float bf_hi(unsigned u) { return __uint_as_float(u & 0xffff0000u); }

// ---------------------------------------------------------------------------
// Graph build, stage 1: bucket histogram (LDS-staged).
// ---------------------------------------------------------------------------
__global__ __launch_bounds__(256) void hist_k(const int* __restrict__ dst, int e,
                                              int* __restrict__ bcnt) {
    __shared__ int h[MAX_BUCKETS];
    const int t = threadIdx.x;
    if (t < MAX_BUCKETS) h[t] = 0;
    __syncthreads();
    const int i0 = blockIdx.x * 4096;
#pragma unroll
    for (int k = 0; k < 16; ++k) {
        int i = i0 + t + k * 256;
        if (i < e) atomicAdd(&h[dst[i] >> 10], 1);
    }
    __syncthreads();
    if (t < MAX_BUCKETS && h[t]) atomicAdd(&bcnt[t], h[t]);
}

// Stage 2: one-wave exclusive scan of bucket counts -> bases + cursors.
__global__ __launch_bounds__(64) void bscan64_k(const int* __restrict__ bcnt,
                                                int* __restrict__ bbase,
                                                int* __restrict__ gcur,
                                                int nb, int e) {
    const int t = threadIdx.x;
    int v = (t < nb) ? bcnt[t] : 0;
    int x = v;
#pragma unroll
    for (int off = 1; off < 64; off <<= 1) {
        int y = __shfl_up(x, off);
        if (t >= off) x += y;
    }
    int excl = x - v;
    if (t < nb) {
        bbase[t] = excl;
        gcur[t] = excl;
    }
    if (t == nb) bbase[t] = e;
}

// Stage 3: scatter (src,dst) pairs into bucket segments.  Each block reserves
// a contiguous chunk per bucket (one global atomic per block x bucket), so
// pair writes land in ~1.3KB single-writer runs instead of random 8B.
__global__ __launch_bounds__(512) void scatter_k(const int* __restrict__ src,
                                                 const int* __restrict__ dst,
                                                 int e, int* __restrict__ gcur,
                                                 uint2* __restrict__ pairs) {
    __shared__ int cnt[MAX_BUCKETS];
    __shared__ int cur[MAX_BUCKETS];
    __shared__ int gb[MAX_BUCKETS];
    const int t = threadIdx.x;
    if (t < MAX_BUCKETS) cnt[t] = 0;
    __syncthreads();
    const int i0 = blockIdx.x * 8192;
    int d[16];
#pragma unroll
    for (int k = 0; k < 16; ++k) {
        int i = i0 + t + k * 512;
        d[k] = (i < e) ? dst[i] : -1;
        if (d[k] >= 0) atomicAdd(&cnt[d[k] >> 10], 1);
    }
    __syncthreads();
    if (t < MAX_BUCKETS) {
        gb[t] = cnt[t] ? atomicAdd(&gcur[t], cnt[t]) : 0;
        cur[t] = 0;
    }
    __syncthreads();
#pragma unroll
    for (int k = 0; k < 16; ++k) {
        int i = i0 + t + k * 512;
        if (d[k] >= 0) {
            int b = d[k] >> 10;
            int r = atomicAdd(&cur[b], 1);
            pairs[gb[b] + r] = make_uint2((unsigned)src[i], (unsigned)d[k]);
        }
    }
}

// Stage 4: per-bucket CSR build.  One 1024-thread workgroup owns one bucket:
// LDS histogram of its 1024 nodes -> local scan -> rp/dinv/col.
__global__ __launch_bounds__(1024) void build_k(const uint2* __restrict__ pairs,
                                                const int* __restrict__ bbase,
                                                int n, int e,
                                                int* __restrict__ rp,
                                                float* __restrict__ dinv,
                                                int* __restrict__ col) {
    __shared__ int hist[1024];
    __shared__ int tsum[1024];
    const int t = threadIdx.x;
    const int node0 = blockIdx.x << 10;
    hist[t] = 0;
    __syncthreads();
    const int ebase = bbase[blockIdx.x];
    const int eend = bbase[blockIdx.x + 1];
    for (int i = ebase + t; i < eend; i += 1024) {
        uint2 p = pairs[i];
        atomicAdd(&hist[(int)p.y - node0], 1);
    }
    __syncthreads();
    const int deg = hist[t];
    tsum[t] = deg;
    __syncthreads();
    for (int off = 1; off < 1024; off <<= 1) {
        int x = (t >= off) ? tsum[t - off] : 0;
        __syncthreads();
        tsum[t] += x;
        __syncthreads();
    }
    const int excl = tsum[t] - deg;
    if (node0 + t < n) {
        rp[node0 + t] = ebase + excl;
        dinv[node0 + t] = rsqrtf((float)(deg + 1));
    }
    hist[t] = excl;                       // local fill cursor
    __syncthreads();
    for (int i = ebase + t; i < eend; i += 1024) {
        uint2 p = pairs[i];
        int r = atomicAdd(&hist[(int)p.y - node0], 1);
        col[ebase + r] = (int)p.x;
    }
    if (blockIdx.x == 0 && t == 0) rp[n] = e;
}

// ---------------------------------------------------------------------------
// GEMM: G[r][c] = dinv[r] * sum_k X[r][k] * W[k][c];  K = 128 fixed.
// 128 rows/block, 256 threads as 16x16, each thread 8 rows x (OUT/16) cols.
// Output stored as packed bf16 (2 cols per uint).
// ---------------------------------------------------------------------------
template <int OUT>
__global__ __launch_bounds__(256) void gemm_scale_k(const float* __restrict__ X,
                                                    const float* __restrict__ W,
                                                    const float* __restrict__ dinv,
                                                    unsigned* __restrict__ Gb, int n) {
    constexpr int CPT = OUT / 16;                 // cols per thread: 8 or 4
    __shared__ float xs[128][33];                 // 32 k + 1 pad (stride 33)
    __shared__ float ws[32][OUT];

    const int tid = threadIdx.x;
    const int tx = tid & 15;
    const int ty = tid >> 4;
    const int row0 = blockIdx.x * 128;

    float acc[8][CPT];
#pragma unroll
    for (int i = 0; i < 8; ++i)
#pragma unroll
        for (int j = 0; j < CPT; ++j) acc[i][j] = 0.f;

    for (int kc = 0; kc < 4; ++kc) {
        __syncthreads();
#pragma unroll
        for (int p = 0; p < 4; ++p) {
            int idx = p * 256 + tid;              // float4 index
            int r = idx >> 3;                     // 8 float4 per row
            int c4 = idx & 7;
            float4 v = make_float4(0.f, 0.f, 0.f, 0.f);
            if (row0 + r < n)
                v = *(const float4*)&X[(size_t)(row0 + r) * 128 + kc * 32 + c4 * 4];
            xs[r][c4 * 4 + 0] = v.x;
            xs[r][c4 * 4 + 1] = v.y;
            xs[r][c4 * 4 + 2] = v.z;
            xs[r][c4 * 4 + 3] = v.w;
        }
#pragma unroll
        for (int p = 0; p < (32 * OUT) / 1024; ++p) {
            int idx = p * 256 + tid;              // float4 index
            int r = idx / (OUT / 4);
            int c4 = idx % (OUT / 4);
            *(float4*)&ws[r][c4 * 4] =
                *(const float4*)&W[(size_t)(kc * 32 + r) * OUT + c4 * 4];
        }
        __syncthreads();
#pragma unroll 8
        for (int k = 0; k < 32; ++k) {
            float a[8], b[CPT];
#pragma unroll
            for (int i = 0; i < 8; ++i) a[i] = xs[ty * 8 + i][k];
#pragma unroll
            for (int j = 0; j < CPT; ++j) b[j] = ws[k][tx * CPT + j];
#pragma unroll
            for (int i = 0; i < 8; ++i)
#pragma unroll
                for (int j = 0; j < CPT; ++j) acc[i][j] += a[i] * b[j];
        }
    }

    // epilogue: scale by dinv[r], pack to bf16 (2 cols / uint)
#pragma unroll
    for (int i = 0; i < 8; ++i) {
        int r = row0 + ty * 8 + i;
        if (r < n) {
            float d = dinv[r];
            unsigned pk[CPT / 2];
#pragma unroll
            for (int j = 0; j < CPT / 2; ++j)
                pk[j] = bf16_rn(d * acc[i][j * 2]) |
                        (bf16_rn(d * acc[i][j * 2 + 1]) << 16);
            unsigned* rowp = &Gb[(size_t)r * (OUT / 2) + tx * (CPT / 2)];
            if (CPT == 8) *(uint4*)rowp = make_uint4(pk[0], pk[1], pk[2], pk[3]);
            else          *(uint2*)rowp = make_uint2(pk[0], pk[1]);
        }
    }
}

// ---------------------------------------------------------------------------
// Aggregation, hidden layers (OUT=128): one wave per node, lane = 2 columns
// (one packed-bf16 uint per lane).  f32 accumulate, swish, f32 H out.
// ---------------------------------------------------------------------------
__global__ __launch_bounds__(256) void agg_swish_k(const unsigned* __restrict__ G,
                                                   const int* __restrict__ rp,
                                                   const int* __restrict__ col,
                                                   const float* __restrict__ dinv,
                                                   const float* __restrict__ bias,
                                                   float* __restrict__ H, int n) {
    const int wave = (blockIdx.x * blockDim.x + threadIdx.x) >> 6;
    const int lane = threadIdx.x & 63;
    if (wave >= n) return;
    const int i = wave;

    unsigned u = G[(size_t)i * 64 + lane];        // self-loop (row = 64 uints)
    float ax = bf_lo(u), ay = bf_hi(u);
    const int s = rp[i], e = rp[i + 1];
    int p = s;
    for (; p + 4 <= e; p += 4) {
        int j0 = col[p + 0], j1 = col[p + 1], j2 = col[p + 2], j3 = col[p + 3];
        unsigned u0 = G[(size_t)j0 * 64 + lane];
        unsigned u1 = G[(size_t)j1 * 64 + lane];
        unsigned u2 = G[(size_t)j2 * 64 + lane];
        unsigned u3 = G[(size_t)j3 * 64 + lane];
        ax += (bf_lo(u0) + bf_lo(u1)) + (bf_lo(u2) + bf_lo(u3));
        ay += (bf_hi(u0) + bf_hi(u1)) + (bf_hi(u2) + bf_hi(u3));
    }
    for (; p < e; ++p) {
        unsigned v = G[(size_t)col[p] * 64 + lane];
        ax += bf_lo(v);
        ay += bf_hi(v);
    }
    const float d = dinv[i];
    float rx = d * ax + bias[lane * 2 + 0];
    float ry = d * ay + bias[lane * 2 + 1];
    rx = rx / (1.f + expf(-rx));                  // swish
    ry = ry / (1.f + expf(-ry));
    float2 o;
    o.x = rx;
    o.y = ry;
    *(float2*)&H[(size_t)i * 128 + lane * 2] = o;
}

// ---------------------------------------------------------------------------
// Final aggregation (OUT=64, bf16 rows of 128B) + log_softmax.
// ---------------------------------------------------------------------------
__global__ __launch_bounds__(256) void agg_lsm_k(const unsigned short* __restrict__ G,
                                                 const int* __restrict__ rp,
                                                 const int* __restrict__ col,
                                                 const float* __restrict__ dinv,
                                                 const float* __restrict__ bias,
                                                 float* __restrict__ out, int n) {
    const int wave = (blockIdx.x * blockDim.x + threadIdx.x) >> 6;
    const int lane = threadIdx.x & 63;
    if (wave >= n) return;
    const int i = wave;

    float acc = __uint_as_float((unsigned)G[(size_t)i * 64 + lane] << 16);
    const int s = rp[i], e = rp[i + 1];
    int p = s;
    for (; p + 4 <= e; p += 4) {
        int j0 = col[p + 0], j1 = col[p + 1], j2 = col[p + 2], j3 = col[p + 3];
        float v0 = __uint_as_float((unsigned)G[(size_t)j0 * 64 + lane] << 16);
        float v1 = __uint_as_float((unsigned)G[(size_t)j1 * 64 + lane] << 16);
        float v2 = __uint_as_float((unsigned)G[(size_t)j2 * 64 + lane] << 16);
        float v3 = __uint_as_float((unsigned)G[(size_t)j3 * 64 + lane] << 16);
        acc += (v0 + v1) + (v2 + v3);
    }
    for (; p < e; ++p)
        acc += __uint_as_float((unsigned)G[(size_t)col[p] * 64 + lane] << 16);

    float logit = dinv[i] * acc + bias[lane];
    float m = logit;
#pragma unroll
    for (int off = 32; off > 0; off >>= 1) m = fmaxf(m, __shfl_xor(m, off));
    float ex = expf(logit - m);
    float ssum = ex;
#pragma unroll
    for (int off = 32; off > 0; off >>= 1) ssum += __shfl_xor(ssum, off);
    out[(size_t)i * 64 + lane] = logit - m - logf(ssum);
}

extern "C" void kernel_launch(void* const* d_in, const int* in_sizes, int n_in,
                              void* d_out, int out_size, void* d_ws, size_t ws_size,
                              hipStream_t stream) {
    const float* x = (const float*)d_in[0];
    const int* ei = (const int*)d_in[1];
    const float* W0 = (const float*)d_in[2];
    const float* b0 = (const float*)d_in[3];
    const float* W1 = (const float*)d_in[4];
    const float* b1 = (const float*)d_in[5];
    const float* W2 = (const float*)d_in[6];
    const float* b2 = (const float*)d_in[7];
    float* out = (float*)d_out;

    const int n = in_sizes[0] / 128;
    const int e = in_sizes[1] / 2;
    const int* src = ei;
    const int* dst = ei + e;

    char* ws = (char*)d_ws;
    size_t off = 0;
    auto alloc = [&](size_t bytes) -> void* {
        void* p = ws + off;
        off += (bytes + 255) & ~(size_t)255;
        return p;
    };
    int* bcnt = (int*)alloc(MAX_BUCKETS * 4);      // bucket histogram
    int* bbase = (int*)alloc((MAX_BUCKETS + 1) * 4);
    int* gcur = (int*)alloc(MAX_BUCKETS * 4);      // bucket fill cursors
    int* rp = (int*)alloc((size_t)(n + 1) * 4);    // CSR row_ptr
    float* dinv = (float*)alloc((size_t)n * 4);
    int* col = (int*)alloc((size_t)e * 4);         // CSR col (src per dst)
    uint2* pairs = (uint2*)alloc((size_t)e * 8);   // bucketed (src,dst)
    unsigned* g = (unsigned*)alloc((size_t)n * 64 * 4); // bf16 pre-agg features
    float* h = (float*)alloc((size_t)n * 128 * 4); // post-activation features

    const int nbuck = (n + NODES_PER_BUCKET - 1) / NODES_PER_BUCKET;  // 49

    hipMemsetAsync(bcnt, 0, MAX_BUCKETS * 4, stream);
    hist_k<<<(e + 4095) / 4096, 256, 0, stream>>>(dst, e, bcnt);
    bscan64_k<<<1, 64, 0, stream>>>(bcnt, bbase, gcur, nbuck, e);
    scatter_k<<<(e + 8191) / 8192, 512, 0, stream>>>(src, dst, e, gcur, pairs);
    build_k<<<nbuck, 1024, 0, stream>>>(pairs, bbase, n, e, rp, dinv, col);

    const int gb = (n + 127) / 128;
    const int ab = (n + 3) / 4;                    // 4 waves (nodes) per block

    gemm_scale_k<128><<<gb, 256, 0, stream>>>(x, W0, dinv, g, n);
    agg_swish_k<<<ab, 256, 0, stream>>>(g, rp, col, dinv, b0, h, n);
    gemm_scale_k<128><<<gb, 256, 0, stream>>>(h, W1, dinv, g, n);
    agg_swish_k<<<ab, 256, 0, stream>>>(g, rp, col, dinv, b1, h, n);
    gemm_scale_k<64><<<gb, 256, 0, stream>>>(h, W2, dinv, g, n);
    agg_lsm_k<<<ab, 256, 0, stream>>>((const unsigned short*)g, rp, col, dinv, b2, out, n);
}

// Round 5
// 213.742 us; speedup vs baseline: 2.2116x; 1.2224x over previous
//
#include <hip/hip_runtime.h>

// ---------------------------------------------------------------------------
// GCN: 3-layer, N=50000 nodes, E=800000 edges, F_IN=128, H=128, C=64.
//   norm[e] = dinv[src]*dinv[dst]  =>  fold dinv into GEMM epilogue and
//   aggregation epilogue.  Self-loop = + g[i].
//   layer: g = dinv .* (A @ W);  h = act(dinv[i]*(g[i] + sum_{j->i} g[j]) + b)
// R2: hierarchical scan. R3: G bf16. R4: bucketed counting-sort graph build.
// R5: GEMMs moved to MFMA (16x16x32 bf16), feature path bf16 end-to-end:
//     x converted to bf16 once, H stored bf16 by agg, W transposed to bf16.
//     LDS tiles XOR-swizzled (byte ^= (row&7)<<4) for conflict-free
//     ds_read_b128 column-slice fragment reads (T2).
// ---------------------------------------------------------------------------

#define NODES_PER_BUCKET 1024      // bucket = dst >> 10
#define MAX_BUCKETS 64             // n <= 64K nodes (50000 -> 49 buckets)

typedef __attribute__((ext_vector_type(8))) short short8;
typedef __attribute__((ext_vector_type(4))) float f32x4;

__device__ inline unsigned bf16_rn(float x) {          // rne, no NaN expected
    unsigned u = __float_as_uint(x);
    return (u + 0x7fffu + ((u >> 16) & 1u)) >> 16;
}
__device__ inline float bf_lo(unsigned u) { return __uint_as_float(u << 16); }
__device__ inline float bf_hi(unsigned u) { return __uint_as_float(u & 0xffff0000u); }

// ---------------------------------------------------------------------------
// Graph build (R4): bucket histogram -> scan -> chunked pair scatter ->
// per-bucket CSR build.
// ---------------------------------------------------------------------------
__global__ __launch_bounds__(256) void hist_k(const int* __restrict__ dst, int e,
                                              int* __restrict__ bcnt) {
    __shared__ int h[MAX_BUCKETS];
    const int t = threadIdx.x;
    if (t < MAX_BUCKETS) h[t] = 0;
    __syncthreads();
    const int i0 = blockIdx.x * 4096;
#pragma unroll
    for (int k = 0; k < 16; ++k) {
        int i = i0 + t + k * 256;
        if (i < e) atomicAdd(&h[dst[i] >> 10], 1);
    }
    __syncthreads();
    if (t < MAX_BUCKETS && h[t]) atomicAdd(&bcnt[t], h[t]);
}

__global__ __launch_bounds__(64) void bscan64_k(const int* __restrict__ bcnt,
                                                int* __restrict__ bbase,
                                                int* __restrict__ gcur,
                                                int nb, int e) {
    const int t = threadIdx.x;
    int v = (t < nb) ? bcnt[t] : 0;
    int x = v;
#pragma unroll
    for (int off = 1; off < 64; off <<= 1) {
        int y = __shfl_up(x, off);
        if (t >= off) x += y;
    }
    int excl = x - v;
    if (t < nb) {
        bbase[t] = excl;
        gcur[t] = excl;
    }
    if (t == nb) bbase[t] = e;
}

__global__ __launch_bounds__(512) void scatter_k(const int* __restrict__ src,
                                                 const int* __restrict__ dst,
                                                 int e, int* __restrict__ gcur,
                                                 uint2* __restrict__ pairs) {
    __shared__ int cnt[MAX_BUCKETS];
    __shared__ int cur[MAX_BUCKETS];
    __shared__ int gb[MAX_BUCKETS];
    const int t = threadIdx.x;
    if (t < MAX_BUCKETS) cnt[t] = 0;
    __syncthreads();
    const int i0 = blockIdx.x * 8192;
    int d[16];
#pragma unroll
    for (int k = 0; k < 16; ++k) {
        int i = i0 + t + k * 512;
        d[k] = (i < e) ? dst[i] : -1;
        if (d[k] >= 0) atomicAdd(&cnt[d[k] >> 10], 1);
    }
    __syncthreads();
    if (t < MAX_BUCKETS) {
        gb[t] = cnt[t] ? atomicAdd(&gcur[t], cnt[t]) : 0;
        cur[t] = 0;
    }
    __syncthreads();
#pragma unroll
    for (int k = 0; k < 16; ++k) {
        int i = i0 + t + k * 512;
        if (d[k] >= 0) {
            int b = d[k] >> 10;
            int r = atomicAdd(&cur[b], 1);
            pairs[gb[b] + r] = make_uint2((unsigned)src[i], (unsigned)d[k]);
        }
    }
}

__global__ __launch_bounds__(1024) void build_k(const uint2* __restrict__ pairs,
                                                const int* __restrict__ bbase,
                                                int n, int e,
                                                int* __restrict__ rp,
                                                float* __restrict__ dinv,
                                                int* __restrict__ col) {
    __shared__ int hist[1024];
    __shared__ int tsum[1024];
    const int t = threadIdx.x;
    const int node0 = blockIdx.x << 10;
    hist[t] = 0;
    __syncthreads();
    const int ebase = bbase[blockIdx.x];
    const int eend = bbase[blockIdx.x + 1];
    for (int i = ebase + t; i < eend; i += 1024) {
        uint2 p = pairs[i];
        atomicAdd(&hist[(int)p.y - node0], 1);
    }
    __syncthreads();
    const int deg = hist[t];
    tsum[t] = deg;
    __syncthreads();
    for (int off = 1; off < 1024; off <<= 1) {
        int x = (t >= off) ? tsum[t - off] : 0;
        __syncthreads();
        tsum[t] += x;
        __syncthreads();
    }
    const int excl = tsum[t] - deg;
    if (node0 + t < n) {
        rp[node0 + t] = ebase + excl;
        dinv[node0 + t] = rsqrtf((float)(deg + 1));
    }
    hist[t] = excl;                       // local fill cursor
    __syncthreads();
    for (int i = ebase + t; i < eend; i += 1024) {
        uint2 p = pairs[i];
        int r = atomicAdd(&hist[(int)p.y - node0], 1);
        col[ebase + r] = (int)p.x;
    }
    if (blockIdx.x == 0 && t == 0) rp[n] = e;
}

// ---------------------------------------------------------------------------
// Dtype prep: x f32 -> bf16 (packed), W f32 [128][OUT] -> bf16 Wt [OUT][128].
// ---------------------------------------------------------------------------
__global__ __launch_bounds__(256) void cvtx_k(const float* __restrict__ x,
                                              uint4* __restrict__ xb, int n16) {
    int id = blockIdx.x * 256 + threadIdx.x;   // one uint4 out = 8 floats in
    if (id >= n16) return;
    const float4* xin = (const float4*)x;
    float4 v0 = xin[id * 2], v1 = xin[id * 2 + 1];
    uint4 o;
    o.x = bf16_rn(v0.x) | (bf16_rn(v0.y) << 16);
    o.y = bf16_rn(v0.z) | (bf16_rn(v0.w) << 16);
    o.z = bf16_rn(v1.x) | (bf16_rn(v1.y) << 16);
    o.w = bf16_rn(v1.z) | (bf16_rn(v1.w) << 16);
    xb[id] = o;
}

__global__ __launch_bounds__(256) void cvtw_k(const float* __restrict__ W,
                                              unsigned short* __restrict__ Wt,
                                              int out, int total) {
    int id = blockIdx.x * 256 + threadIdx.x;   // id = o*128 + k
    if (id >= total) return;
    int o = id >> 7, k = id & 127;
    Wt[id] = (unsigned short)bf16_rn(W[k * out + o]);
}

// ---------------------------------------------------------------------------
// MFMA GEMM: G[r][c] = bf16( dinv[r] * sum_k A[r][k]*Wt[c][k] ), K=128.
// Block: 128 rows x OUT cols, 4 waves, wave = 32 rows x OUT cols.
// mfma_f32_16x16x32_bf16; fragment layout (m89/m91-verified family):
//   A: row=lane&15, k=(lane>>4)*8+j;  B: col=lane&15, same k;
//   D: col=lane&15, row=(lane>>4)*4+reg.
// LDS XOR-swizzle: byte ^= ((row&7)<<4); applied on ds_write AND ds_read.
// ---------------------------------------------------------------------------
template <int OUT>
__global__ __launch_bounds__(256) void mfma_gemm_k(
    const unsigned short* __restrict__ A,    // [n][128] bf16
    const unsigned short* __restrict__ Wt,   // [OUT][128] bf16
    const float* __restrict__ dinv,
    unsigned short* __restrict__ G,          // [n][OUT] bf16
    int n) {
    constexpr int NF = OUT / 16;             // col fragments per wave
    __shared__ unsigned short lds[(128 + OUT) * 128];
    unsigned short* As = lds;                // 128 rows x 256B (swizzled)
    unsigned short* Ws = lds + 128 * 128;    // OUT rows x 256B (swizzled)

    const int tid = threadIdx.x;
    const int row0 = blockIdx.x * 128;

    // stage A tile: 128 rows x 16 chunks of 16B
#pragma unroll
    for (int p = 0; p < 8; ++p) {
        int id = p * 256 + tid;
        int r = id >> 4, c = id & 15;
        uint4 v = make_uint4(0, 0, 0, 0);
        if (row0 + r < n)
            v = *(const uint4*)&A[(size_t)(row0 + r) * 128 + c * 8];
        int bo = r * 256 + ((c * 16) ^ ((r & 7) << 4));
        *(uint4*)((char*)As + bo) = v;
    }
    // stage Wt tile: OUT rows x 16 chunks
#pragma unroll
    for (int p = 0; p < OUT / 16; ++p) {
        int id = p * 256 + tid;
        int r = id >> 4, c = id & 15;
        uint4 v = *(const uint4*)&Wt[(size_t)r * 128 + c * 8];
        int bo = r * 256 + ((c * 16) ^ ((r & 7) << 4));
        *(uint4*)((char*)Ws + bo) = v;
    }
    __syncthreads();

    const int wid = tid >> 6, lane = tid & 63;
    const int lq = lane >> 4, lr = lane & 15;
    const int woff = wid * 32;

    f32x4 acc[2][NF] = {};
#pragma unroll
    for (int ks = 0; ks < 4; ++ks) {
        short8 a[2];
#pragma unroll
        for (int m = 0; m < 2; ++m) {
            int r = woff + m * 16 + lr;
            int bo = r * 256 + ((lq * 16 + ks * 64) ^ ((r & 7) << 4));
            a[m] = *(const short8*)((const char*)As + bo);
        }
#pragma unroll
        for (int nf = 0; nf < NF; ++nf) {
            int c = nf * 16 + lr;
            int bo = c * 256 + ((lq * 16 + ks * 64) ^ ((c & 7) << 4));
            short8 b = *(const short8*)((const char*)Ws + bo);
            acc[0][nf] = __builtin_amdgcn_mfma_f32_16x16x32_bf16(a[0], b, acc[0][nf], 0, 0, 0);
            acc[1][nf] = __builtin_amdgcn_mfma_f32_16x16x32_bf16(a[1], b, acc[1][nf], 0, 0, 0);
        }
    }

    // epilogue: scale by dinv, pack bf16
#pragma unroll
    for (int m = 0; m < 2; ++m) {
#pragma unroll
        for (int j = 0; j < 4; ++j) {
            int r = row0 + woff + m * 16 + lq * 4 + j;
            if (r < n) {
                float d = dinv[r];
#pragma unroll
                for (int nf = 0; nf < NF; ++nf)
                    G[(size_t)r * OUT + nf * 16 + lr] =
                        (unsigned short)bf16_rn(d * acc[m][nf][j]);
            }
        }
    }
}

// ---------------------------------------------------------------------------
// Aggregation, hidden layers: one wave per node, lane = 2 cols (packed bf16).
// f32 accumulate, swish, bf16 packed H out (feeds next MFMA GEMM).
// ---------------------------------------------------------------------------
__global__ __launch_bounds__(256) void agg_swish_k(const unsigned* __restrict__ G,
                                                   const int* __restrict__ rp,
                                                   const int* __restrict__ col,
                                                   const float* __restrict__ dinv,
                                                   const float* __restrict__ bias,
                                                   unsigned* __restrict__ Hb, int n) {
    const int wave = (blockIdx.x * blockDim.x + threadIdx.x) >> 6;
    const int lane = threadIdx.x & 63;
    if (wave >= n) return;
    const int i = wave;

    unsigned u = G[(size_t)i * 64 + lane];        // self-loop (row = 64 uints)
    float ax = bf_lo(u), ay = bf_hi(u);
    const int s = rp[i], e = rp[i + 1];
    int p = s;
    for (; p + 4 <= e; p += 4) {
        int j0 = col[p + 0], j1 = col[p + 1], j2 = col[p + 2], j3 = col[p + 3];
        unsigned u0 = G[(size_t)j0 * 64 + lane];
        unsigned u1 = G[(size_t)j1 * 64 + lane];
        unsigned u2 = G[(size_t)j2 * 64 + lane];
        unsigned u3 = G[(size_t)j3 * 64 + lane];
        ax += (bf_lo(u0) + bf_lo(u1)) + (bf_lo(u2) + bf_lo(u3));
        ay += (bf_hi(u0) + bf_hi(u1)) + (bf_hi(u2) + bf_hi(u3));
    }
    for (; p < e; ++p) {
        unsigned v = G[(size_t)col[p] * 64 + lane];
        ax += bf_lo(v);
        ay += bf_hi(v);
    }
    const float d = dinv[i];
    float rx = d * ax + bias[lane * 2 + 0];
    float ry = d * ay + bias[lane * 2 + 1];
    rx = rx / (1.f + expf(-rx));                  // swish
    ry = ry / (1.f + expf(-ry));
    Hb[(size_t)i * 64 + lane] = bf16_rn(rx) | (bf16_rn(ry) << 16);
}

// ---------------------------------------------------------------------------
// Final aggregation (OUT=64, bf16 rows of 128B) + log_softmax.
// ---------------------------------------------------------------------------
__global__ __launch_bounds__(256) void agg_lsm_k(const unsigned short* __restrict__ G,
                                                 const int* __restrict__ rp,
                                                 const int* __restrict__ col,
                                                 const float* __restrict__ dinv,
                                                 const float* __restrict__ bias,
                                                 float* __restrict__ out, int n) {
    const int wave = (blockIdx.x * blockDim.x + threadIdx.x) >> 6;
    const int lane = threadIdx.x & 63;
    if (wave >= n) return;
    const int i = wave;

    float acc = __uint_as_float((unsigned)G[(size_t)i * 64 + lane] << 16);
    const int s = rp[i], e = rp[i + 1];
    int p = s;
    for (; p + 4 <= e; p += 4) {
        int j0 = col[p + 0], j1 = col[p + 1], j2 = col[p + 2], j3 = col[p + 3];
        float v0 = __uint_as_float((unsigned)G[(size_t)j0 * 64 + lane] << 16);
        float v1 = __uint_as_float((unsigned)G[(size_t)j1 * 64 + lane] << 16);
        float v2 = __uint_as_float((unsigned)G[(size_t)j2 * 64 + lane] << 16);
        float v3 = __uint_as_float((unsigned)G[(size_t)j3 * 64 + lane] << 16);
        acc += (v0 + v1) + (v2 + v3);
    }
    for (; p < e; ++p)
        acc += __uint_as_float((unsigned)G[(size_t)col[p] * 64 + lane] << 16);

    float logit = dinv[i] * acc + bias[lane];
    float m = logit;
#pragma unroll
    for (int off = 32; off > 0; off >>= 1) m = fmaxf(m, __shfl_xor(m, off));
    float ex = expf(logit - m);
    float ssum = ex;
#pragma unroll
    for (int off = 32; off > 0; off >>= 1) ssum += __shfl_xor(ssum, off);
    out[(size_t)i * 64 + lane] = logit - m - logf(ssum);
}

extern "C" void kernel_launch(void* const* d_in, const int* in_sizes, int n_in,
                              void* d_out, int out_size, void* d_ws, size_t ws_size,
                              hipStream_t stream) {
    const float* x = (const float*)d_in[0];
    const int* ei = (const int*)d_in[1];
    const float* W0 = (const float*)d_in[2];
    const float* b0 = (const float*)d_in[3];
    const float* W1 = (const float*)d_in[4];
    const float* b1 = (const float*)d_in[5];
    const float* W2 = (const float*)d_in[6];
    const float* b2 = (const float*)d_in[7];
    float* out = (float*)d_out;

    const int n = in_sizes[0] / 128;
    const int e = in_sizes[1] / 2;
    const int* src = ei;
    const int* dst = ei + e;

    char* ws = (char*)d_ws;
    size_t off = 0;
    auto alloc = [&](size_t bytes) -> void* {
        void* p = ws + off;
        off += (bytes + 255) & ~(size_t)255;
        return p;
    };
    int* bcnt = (int*)alloc(MAX_BUCKETS * 4);      // bucket histogram
    int* bbase = (int*)alloc((MAX_BUCKETS + 1) * 4);
    int* gcur = (int*)alloc(MAX_BUCKETS * 4);      // bucket fill cursors
    int* rp = (int*)alloc((size_t)(n + 1) * 4);    // CSR row_ptr
    float* dinv = (float*)alloc((size_t)n * 4);
    int* col = (int*)alloc((size_t)e * 4);         // CSR col (src per dst)
    uint2* pairs = (uint2*)alloc((size_t)e * 8);   // bucketed (src,dst)
    unsigned short* xb = (unsigned short*)alloc((size_t)n * 256);  // x bf16
    unsigned short* w0t = (unsigned short*)alloc(128 * 128 * 2);
    unsigned short* w1t = (unsigned short*)alloc(128 * 128 * 2);
    unsigned short* w2t = (unsigned short*)alloc(64 * 128 * 2);
    unsigned short* g = (unsigned short*)alloc((size_t)n * 256);   // bf16 pre-agg
    unsigned short* hb = (unsigned short*)alloc((size_t)n * 256);  // bf16 post-act

    const int nbuck = (n + NODES_PER_BUCKET - 1) / NODES_PER_BUCKET;  // 49

    hipMemsetAsync(bcnt, 0, MAX_BUCKETS * 4, stream);
    hist_k<<<(e + 4095) / 4096, 256, 0, stream>>>(dst, e, bcnt);
    bscan64_k<<<1, 64, 0, stream>>>(bcnt, bbase, gcur, nbuck, e);
    scatter_k<<<(e + 8191) / 8192, 512, 0, stream>>>(src, dst, e, gcur, pairs);
    build_k<<<nbuck, 1024, 0, stream>>>(pairs, bbase, n, e, rp, dinv, col);

    cvtx_k<<<(n * 16 + 255) / 256, 256, 0, stream>>>(x, (uint4*)xb, n * 16);
    cvtw_k<<<(128 * 128 + 255) / 256, 256, 0, stream>>>(W0, w0t, 128, 128 * 128);
    cvtw_k<<<(128 * 128 + 255) / 256, 256, 0, stream>>>(W1, w1t, 128, 128 * 128);
    cvtw_k<<<(64 * 128 + 255) / 256, 256, 0, stream>>>(W2, w2t, 64, 64 * 128);

    const int gb = (n + 127) / 128;
    const int ab = (n + 3) / 4;                    // 4 waves (nodes) per block

    mfma_gemm_k<128><<<gb, 256, 0, stream>>>(xb, w0t, dinv, g, n);
    agg_swish_k<<<ab, 256, 0, stream>>>((const unsigned*)g, rp, col, dinv, b0,
                                        (unsigned*)hb, n);
    mfma_gemm_k<128><<<gb, 256, 0, stream>>>(hb, w1t, dinv, g, n);
    agg_swish_k<<<ab, 256, 0, stream>>>((const unsigned*)g, rp, col, dinv, b1,
                                        (unsigned*)hb, n);
    mfma_gemm_k<64><<<gb, 256, 0, stream>>>(hb, w2t, dinv, g, n);
    agg_lsm_k<<<ab, 256, 0, stream>>>(g, rp, col, dinv, b2, out, n);
}

// Round 6
// 205.900 us; speedup vs baseline: 2.2958x; 1.0381x over previous
//
#include <hip/hip_runtime.h>

// ---------------------------------------------------------------------------
// GCN: 3-layer, N=50000 nodes, E=800000 edges, F_IN=128, H=128, C=64.
//   norm[e] = dinv[src]*dinv[dst]  =>  fold dinv into GEMM epilogue and
//   aggregation epilogue.  Self-loop = + g[i].
//   layer: g = dinv .* (A @ W);  h = act(dinv[i]*(g[i] + sum_{j->i} g[j]) + b)
// R2: hierarchical scan. R3: G bf16. R4: bucketed counting-sort graph build.
// R5: MFMA GEMMs (16x16x32 bf16), bf16 feature path, XOR-swizzled LDS.
// R6: agg gather latency-bound (41us @ 2.35TB/s, 4 loads in flight) ->
//     8-deep gather unroll (issue all 8 before accumulating);
//     cvtx folded into GEMM-0 staging (F32IN template);
//     3 cvtw launches merged into 1.
// ---------------------------------------------------------------------------

#define NODES_PER_BUCKET 1024      // bucket = dst >> 10
#define MAX_BUCKETS 64             // n <= 64K nodes (50000 -> 49 buckets)

typedef __attribute__((ext_vector_type(8))) short short8;
typedef __attribute__((ext_vector_type(4))) float f32x4;

__device__ inline unsigned bf16_rn(float x) {          // rne, no NaN expected
    unsigned u = __float_as_uint(x);
    return (u + 0x7fffu + ((u >> 16) & 1u)) >> 16;
}
__device__ inline float bf_lo(unsigned u) { return __uint_as_float(u << 16); }
__device__ inline float bf_hi(unsigned u) { return __uint_as_float(u & 0xffff0000u); }

// ---------------------------------------------------------------------------
// Graph build (R4): bucket histogram -> scan -> chunked pair scatter ->
// per-bucket CSR build.
// ---------------------------------------------------------------------------
__global__ __launch_bounds__(256) void hist_k(const int* __restrict__ dst, int e,
                                              int* __restrict__ bcnt) {
    __shared__ int h[MAX_BUCKETS];
    const int t = threadIdx.x;
    if (t < MAX_BUCKETS) h[t] = 0;
    __syncthreads();
    const int i0 = blockIdx.x * 4096;
#pragma unroll
    for (int k = 0; k < 16; ++k) {
        int i = i0 + t + k * 256;
        if (i < e) atomicAdd(&h[dst[i] >> 10], 1);
    }
    __syncthreads();
    if (t < MAX_BUCKETS && h[t]) atomicAdd(&bcnt[t], h[t]);
}

__global__ __launch_bounds__(64) void bscan64_k(const int* __restrict__ bcnt,
                                                int* __restrict__ bbase,
                                                int* __restrict__ gcur,
                                                int nb, int e) {
    const int t = threadIdx.x;
    int v = (t < nb) ? bcnt[t] : 0;
    int x = v;
#pragma unroll
    for (int off = 1; off < 64; off <<= 1) {
        int y = __shfl_up(x, off);
        if (t >= off) x += y;
    }
    int excl = x - v;
    if (t < nb) {
        bbase[t] = excl;
        gcur[t] = excl;
    }
    if (t == nb) bbase[t] = e;
}

__global__ __launch_bounds__(512) void scatter_k(const int* __restrict__ src,
                                                 const int* __restrict__ dst,
                                                 int e, int* __restrict__ gcur,
                                                 uint2* __restrict__ pairs) {
    __shared__ int cnt[MAX_BUCKETS];
    __shared__ int cur[MAX_BUCKETS];
    __shared__ int gb[MAX_BUCKETS];
    const int t = threadIdx.x;
    if (t < MAX_BUCKETS) cnt[t] = 0;
    __syncthreads();
    const int i0 = blockIdx.x * 8192;
    int d[16];
#pragma unroll
    for (int k = 0; k < 16; ++k) {
        int i = i0 + t + k * 512;
        d[k] = (i < e) ? dst[i] : -1;
        if (d[k] >= 0) atomicAdd(&cnt[d[k] >> 10], 1);
    }
    __syncthreads();
    if (t < MAX_BUCKETS) {
        gb[t] = cnt[t] ? atomicAdd(&gcur[t], cnt[t]) : 0;
        cur[t] = 0;
    }
    __syncthreads();
#pragma unroll
    for (int k = 0; k < 16; ++k) {
        int i = i0 + t + k * 512;
        if (d[k] >= 0) {
            int b = d[k] >> 10;
            int r = atomicAdd(&cur[b], 1);
            pairs[gb[b] + r] = make_uint2((unsigned)src[i], (unsigned)d[k]);
        }
    }
}

__global__ __launch_bounds__(1024) void build_k(const uint2* __restrict__ pairs,
                                                const int* __restrict__ bbase,
                                                int n, int e,
                                                int* __restrict__ rp,
                                                float* __restrict__ dinv,
                                                int* __restrict__ col) {
    __shared__ int hist[1024];
    __shared__ int tsum[1024];
    const int t = threadIdx.x;
    const int node0 = blockIdx.x << 10;
    hist[t] = 0;
    __syncthreads();
    const int ebase = bbase[blockIdx.x];
    const int eend = bbase[blockIdx.x + 1];
    for (int i = ebase + t; i < eend; i += 1024) {
        uint2 p = pairs[i];
        atomicAdd(&hist[(int)p.y - node0], 1);
    }
    __syncthreads();
    const int deg = hist[t];
    tsum[t] = deg;
    __syncthreads();
    for (int off = 1; off < 1024; off <<= 1) {
        int x = (t >= off) ? tsum[t - off] : 0;
        __syncthreads();
        tsum[t] += x;
        __syncthreads();
    }
    const int excl = tsum[t] - deg;
    if (node0 + t < n) {
        rp[node0 + t] = ebase + excl;
        dinv[node0 + t] = rsqrtf((float)(deg + 1));
    }
    hist[t] = excl;                       // local fill cursor
    __syncthreads();
    for (int i = ebase + t; i < eend; i += 1024) {
        uint2 p = pairs[i];
        int r = atomicAdd(&hist[(int)p.y - node0], 1);
        col[ebase + r] = (int)p.x;
    }
    if (blockIdx.x == 0 && t == 0) rp[n] = e;
}

// ---------------------------------------------------------------------------
// Weight prep: all three W f32 [128][out] -> bf16 Wt [out][128], one launch.
// segments: w0t 16384 elems, w1t 16384, w2t 8192 (id = o*128 + k).
// ---------------------------------------------------------------------------
__global__ __launch_bounds__(256) void cvtw3_k(const float* __restrict__ W0,
                                               const float* __restrict__ W1,
                                               const float* __restrict__ W2,
                                               unsigned short* __restrict__ Wt) {
    int id = blockIdx.x * 256 + threadIdx.x;        // 0 .. 40959
    if (id >= 40960) return;
    const float* W;
    int out, loc;
    if (id < 16384)       { W = W0; out = 128; loc = id; }
    else if (id < 32768)  { W = W1; out = 128; loc = id - 16384; }
    else                  { W = W2; out = 64;  loc = id - 32768; }
    int o = loc >> 7, k = loc & 127;
    Wt[id] = (unsigned short)bf16_rn(W[k * out + o]);
}

// ---------------------------------------------------------------------------
// MFMA GEMM: G[r][c] = bf16( dinv[r] * sum_k A[r][k]*Wt[c][k] ), K=128.
// Block: 128 rows x OUT cols, 4 waves, wave = 32 rows x OUT cols.
// F32IN: stage converts f32 input rows to bf16 on the fly (layer 0).
// LDS XOR-swizzle: byte ^= ((row&7)<<4) on ds_write AND ds_read (T2).
// ---------------------------------------------------------------------------
template <int OUT, bool F32IN>
__global__ __launch_bounds__(256) void mfma_gemm_k(
    const void* __restrict__ Av,             // [n][128] bf16 or f32
    const unsigned short* __restrict__ Wt,   // [OUT][128] bf16
    const float* __restrict__ dinv,
    unsigned short* __restrict__ G,          // [n][OUT] bf16
    int n) {
    constexpr int NF = OUT / 16;             // col fragments per wave
    __shared__ unsigned short lds[(128 + OUT) * 128];
    unsigned short* As = lds;                // 128 rows x 256B (swizzled)
    unsigned short* Ws = lds + 128 * 128;    // OUT rows x 256B (swizzled)

    const int tid = threadIdx.x;
    const int row0 = blockIdx.x * 128;

    // stage A tile: 128 rows x 16 chunks of 16B (8 bf16)
#pragma unroll
    for (int p = 0; p < 8; ++p) {
        int id = p * 256 + tid;
        int r = id >> 4, c = id & 15;
        uint4 v = make_uint4(0, 0, 0, 0);
        if (row0 + r < n) {
            if (F32IN) {
                const float* Af = (const float*)Av;
                const float4* fp =
                    (const float4*)&Af[(size_t)(row0 + r) * 128 + c * 8];
                float4 v0 = fp[0], v1 = fp[1];
                v.x = bf16_rn(v0.x) | (bf16_rn(v0.y) << 16);
                v.y = bf16_rn(v0.z) | (bf16_rn(v0.w) << 16);
                v.z = bf16_rn(v1.x) | (bf16_rn(v1.y) << 16);
                v.w = bf16_rn(v1.z) | (bf16_rn(v1.w) << 16);
            } else {
                const unsigned short* Ab = (const unsigned short*)Av;
                v = *(const uint4*)&Ab[(size_t)(row0 + r) * 128 + c * 8];
            }
        }
        int bo = r * 256 + ((c * 16) ^ ((r & 7) << 4));
        *(uint4*)((char*)As + bo) = v;
    }
    // stage Wt tile: OUT rows x 16 chunks
#pragma unroll
    for (int p = 0; p < OUT / 16; ++p) {
        int id = p * 256 + tid;
        int r = id >> 4, c = id & 15;
        uint4 v = *(const uint4*)&Wt[(size_t)r * 128 + c * 8];
        int bo = r * 256 + ((c * 16) ^ ((r & 7) << 4));
        *(uint4*)((char*)Ws + bo) = v;
    }
    __syncthreads();

    const int wid = tid >> 6, lane = tid & 63;
    const int lq = lane >> 4, lr = lane & 15;
    const int woff = wid * 32;

    f32x4 acc[2][NF] = {};
#pragma unroll
    for (int ks = 0; ks < 4; ++ks) {
        short8 a[2];
#pragma unroll
        for (int m = 0; m < 2; ++m) {
            int r = woff + m * 16 + lr;
            int bo = r * 256 + ((lq * 16 + ks * 64) ^ ((r & 7) << 4));
            a[m] = *(const short8*)((const char*)As + bo);
        }
#pragma unroll
        for (int nf = 0; nf < NF; ++nf) {
            int c = nf * 16 + lr;
            int bo = c * 256 + ((lq * 16 + ks * 64) ^ ((c & 7) << 4));
            short8 b = *(const short8*)((const char*)Ws + bo);
            acc[0][nf] = __builtin_amdgcn_mfma_f32_16x16x32_bf16(a[0], b, acc[0][nf], 0, 0, 0);
            acc[1][nf] = __builtin_amdgcn_mfma_f32_16x16x32_bf16(a[1], b, acc[1][nf], 0, 0, 0);
        }
    }

    // epilogue: scale by dinv, pack bf16
#pragma unroll
    for (int m = 0; m < 2; ++m) {
#pragma unroll
        for (int j = 0; j < 4; ++j) {
            int r = row0 + woff + m * 16 + lq * 4 + j;
            if (r < n) {
                float d = dinv[r];
#pragma unroll
                for (int nf = 0; nf < NF; ++nf)
                    G[(size_t)r * OUT + nf * 16 + lr] =
                        (unsigned short)bf16_rn(d * acc[m][nf][j]);
            }
        }
    }
}

// ---------------------------------------------------------------------------
// Aggregation, hidden layers: one wave per node, lane = 2 cols (packed bf16).
// 8-deep gather unroll: issue all 8 row loads before accumulating (MLP).
// f32 accumulate, swish, bf16 packed H out.
// ---------------------------------------------------------------------------
__global__ __launch_bounds__(256) void agg_swish_k(const unsigned* __restrict__ G,
                                                   const int* __restrict__ rp,
                                                   const int* __restrict__ col,
                                                   const float* __restrict__ dinv,
                                                   const float* __restrict__ bias,
                                                   unsigned* __restrict__ Hb, int n) {
    const int wave = (blockIdx.x * blockDim.x + threadIdx.x) >> 6;
    const int lane = threadIdx.x & 63;
    if (wave >= n) return;
    const int i = wave;

    unsigned u = G[(size_t)i * 64 + lane];        // self-loop (row = 64 uints)
    float ax = bf_lo(u), ay = bf_hi(u);
    const int s = rp[i], e = rp[i + 1];
    int p = s;
    for (; p + 8 <= e; p += 8) {
        int j[8];
#pragma unroll
        for (int k = 0; k < 8; ++k) j[k] = col[p + k];   // wave-uniform (s_load)
        unsigned v[8];
#pragma unroll
        for (int k = 0; k < 8; ++k) v[k] = G[(size_t)j[k] * 64 + lane];
#pragma unroll
        for (int k = 0; k < 8; ++k) {
            ax += bf_lo(v[k]);
            ay += bf_hi(v[k]);
        }
    }
    for (; p < e; ++p) {
        unsigned v = G[(size_t)col[p] * 64 + lane];
        ax += bf_lo(v);
        ay += bf_hi(v);
    }
    const float d = dinv[i];
    float rx = d * ax + bias[lane * 2 + 0];
    float ry = d * ay + bias[lane * 2 + 1];
    rx = rx / (1.f + expf(-rx));                  // swish
    ry = ry / (1.f + expf(-ry));
    Hb[(size_t)i * 64 + lane] = bf16_rn(rx) | (bf16_rn(ry) << 16);
}

// ---------------------------------------------------------------------------
// Final aggregation (OUT=64, bf16 rows of 128B) + log_softmax.  8-deep MLP.
// ---------------------------------------------------------------------------
__global__ __launch_bounds__(256) void agg_lsm_k(const unsigned short* __restrict__ G,
                                                 const int* __restrict__ rp,
                                                 const int* __restrict__ col,
                                                 const float* __restrict__ dinv,
                                                 const float* __restrict__ bias,
                                                 float* __restrict__ out, int n) {
    const int wave = (blockIdx.x * blockDim.x + threadIdx.x) >> 6;
    const int lane = threadIdx.x & 63;
    if (wave >= n) return;
    const int i = wave;

    float acc = __uint_as_float((unsigned)G[(size_t)i * 64 + lane] << 16);
    const int s = rp[i], e = rp[i + 1];
    int p = s;
    for (; p + 8 <= e; p += 8) {
        int j[8];
#pragma unroll
        for (int k = 0; k < 8; ++k) j[k] = col[p + k];
        unsigned short v[8];
#pragma unroll
        for (int k = 0; k < 8; ++k) v[k] = G[(size_t)j[k] * 64 + lane];
#pragma unroll
        for (int k = 0; k < 8; ++k)
            acc += __uint_as_float((unsigned)v[k] << 16);
    }
    for (; p < e; ++p)
        acc += __uint_as_float((unsigned)G[(size_t)col[p] * 64 + lane] << 16);

    float logit = dinv[i] * acc + bias[lane];
    float m = logit;
#pragma unroll
    for (int off = 32; off > 0; off >>= 1) m = fmaxf(m, __shfl_xor(m, off));
    float ex = expf(logit - m);
    float ssum = ex;
#pragma unroll
    for (int off = 32; off > 0; off >>= 1) ssum += __shfl_xor(ssum, off);
    out[(size_t)i * 64 + lane] = logit - m - logf(ssum);
}

extern "C" void kernel_launch(void* const* d_in, const int* in_sizes, int n_in,
                              void* d_out, int out_size, void* d_ws, size_t ws_size,
                              hipStream_t stream) {
    const float* x = (const float*)d_in[0];
    const int* ei = (const int*)d_in[1];
    const float* W0 = (const float*)d_in[2];
    const float* b0 = (const float*)d_in[3];
    const float* W1 = (const float*)d_in[4];
    const float* b1 = (const float*)d_in[5];
    const float* W2 = (const float*)d_in[6];
    const float* b2 = (const float*)d_in[7];
    float* out = (float*)d_out;

    const int n = in_sizes[0] / 128;
    const int e = in_sizes[1] / 2;
    const int* src = ei;
    const int* dst = ei + e;

    char* ws = (char*)d_ws;
    size_t off = 0;
    auto alloc = [&](size_t bytes) -> void* {
        void* p = ws + off;
        off += (bytes + 255) & ~(size_t)255;
        return p;
    };
    int* bcnt = (int*)alloc(MAX_BUCKETS * 4);      // bucket histogram
    int* bbase = (int*)alloc((MAX_BUCKETS + 1) * 4);
    int* gcur = (int*)alloc(MAX_BUCKETS * 4);      // bucket fill cursors
    int* rp = (int*)alloc((size_t)(n + 1) * 4);    // CSR row_ptr
    float* dinv = (float*)alloc((size_t)n * 4);
    int* col = (int*)alloc((size_t)e * 4);         // CSR col (src per dst)
    uint2* pairs = (uint2*)alloc((size_t)e * 8);   // bucketed (src,dst)
    unsigned short* wt = (unsigned short*)alloc(40960 * 2);  // w0t|w1t|w2t
    unsigned short* g = (unsigned short*)alloc((size_t)n * 256);   // bf16 pre-agg
    unsigned short* hb = (unsigned short*)alloc((size_t)n * 256);  // bf16 post-act

    unsigned short* w0t = wt;
    unsigned short* w1t = wt + 16384;
    unsigned short* w2t = wt + 32768;

    const int nbuck = (n + NODES_PER_BUCKET - 1) / NODES_PER_BUCKET;  // 49

    hipMemsetAsync(bcnt, 0, MAX_BUCKETS * 4, stream);
    cvtw3_k<<<160, 256, 0, stream>>>(W0, W1, W2, wt);
    hist_k<<<(e + 4095) / 4096, 256, 0, stream>>>(dst, e, bcnt);
    bscan64_k<<<1, 64, 0, stream>>>(bcnt, bbase, gcur, nbuck, e);
    scatter_k<<<(e + 8191) / 8192, 512, 0, stream>>>(src, dst, e, gcur, pairs);
    build_k<<<nbuck, 1024, 0, stream>>>(pairs, bbase, n, e, rp, dinv, col);

    const int gb = (n + 127) / 128;
    const int ab = (n + 3) / 4;                    // 4 waves (nodes) per block

    mfma_gemm_k<128, true><<<gb, 256, 0, stream>>>(x, w0t, dinv, g, n);
    agg_swish_k<<<ab, 256, 0, stream>>>((const unsigned*)g, rp, col, dinv, b0,
                                        (unsigned*)hb, n);
    mfma_gemm_k<128, false><<<gb, 256, 0, stream>>>(hb, w1t, dinv, g, n);
    agg_swish_k<<<ab, 256, 0, stream>>>((const unsigned*)g, rp, col, dinv, b1,
                                        (unsigned*)hb, n);
    mfma_gemm_k<64, false><<<gb, 256, 0, stream>>>(hb, w2t, dinv, g, n);
    agg_lsm_k<<<ab, 256, 0, stream>>>(g, rp, col, dinv, b2, out, n);
}